// Round 2
// baseline (2918.015 us; speedup 1.0000x reference)
//
#include <hip/hip_runtime.h>
#include <hip/hip_bf16.h>
#include <stdint.h>

#define IN_DIM 256
#define HID 128

// ---------------- threefry2x32 dropout (JAX partitionable path) -------------
// key = jax.random.key(42) -> (k1,k2) = (0, 42).
// jax_threefry_partitionable=True (modern default):
//   counts = 64-bit iota over flat index; x0 = hi(idx) = 0, x1 = lo(idx) = idx
//   bits = threefry2x32(k1,k2,x0,x1); out = bits[0] ^ bits[1]
__device__ __forceinline__ unsigned rotl32(unsigned x, int r) {
    return (x << r) | (x >> (32 - r));
}

__device__ __forceinline__ float dropout_scale(unsigned idx) {
    const unsigned ks0 = 0u, ks1 = 42u, ks2 = 0x1BD11BF0u; // 0x1BD11BDA ^ 0 ^ 42
    unsigned x0 = 0u + ks0;      // hi 32 bits of 64-bit counter
    unsigned x1 = idx + ks1;     // lo 32 bits
#define TF_ROUND(r) { x0 += x1; x1 = rotl32(x1, r); x1 ^= x0; }
    TF_ROUND(13) TF_ROUND(15) TF_ROUND(26) TF_ROUND(6)
    x0 += ks1; x1 += ks2 + 1u;
    TF_ROUND(17) TF_ROUND(29) TF_ROUND(16) TF_ROUND(24)
    x0 += ks2; x1 += ks0 + 2u;
    TF_ROUND(13) TF_ROUND(15) TF_ROUND(26) TF_ROUND(6)
    x0 += ks0; x1 += ks1 + 3u;
    TF_ROUND(17) TF_ROUND(29) TF_ROUND(16) TF_ROUND(24)
    x0 += ks1; x1 += ks2 + 4u;
    TF_ROUND(13) TF_ROUND(15) TF_ROUND(26) TF_ROUND(6)
    x0 += ks2; x1 += ks0 + 5u;
#undef TF_ROUND
    unsigned bits = x0 ^ x1;
    float u = __uint_as_float(0x3F800000u | (bits >> 9)) - 1.0f;
    return (u < 0.9f) ? (1.0f / 0.9f) : 0.0f;
}

// ---------------- degree / dinv ---------------------------------------------
__global__ void deg_init(float* deg, int n) {
    int i = blockIdx.x * blockDim.x + threadIdx.x;
    if (i < n) deg[i] = 1.0f; // self-loop
}

__global__ void deg_count(const int* __restrict__ dst, float* __restrict__ deg, int E) {
    int stride = gridDim.x * blockDim.x;
    for (int i = blockIdx.x * blockDim.x + threadIdx.x; i < E; i += stride)
        atomicAdd(&deg[dst[i]], 1.0f);
}

__global__ void deg_rsqrt(float* deg, int n) {
    int i = blockIdx.x * blockDim.x + threadIdx.x;
    if (i < n) deg[i] = 1.0f / sqrtf(deg[i]);
}

// ---------------- fp32 GEMM: C[M x 128] = A[M x K] @ W[128 x K]^T -----------
#define BM 64
#define BN 128
#define BK 16
__global__ __launch_bounds__(256) void gemm_xwT(const float* __restrict__ A,
                                                const float* __restrict__ W,
                                                float* __restrict__ C,
                                                int M, int K) {
    __shared__ float As[BM][BK];
    __shared__ float Bs[BK][BN];
    const int block_m = blockIdx.x * BM;
    const int t = threadIdx.x;
    const int tr = t >> 5;   // 0..7  (row group, 8 rows each)
    const int tc = t & 31;   // 0..31 (col group, 4 cols each)
    const int ar = t >> 2;          // A-load row 0..63
    const int ak = (t & 3) * 4;     // A-load k offset
    const int wn = t >> 1;          // W-load row (n) 0..127
    const int wk0 = (t & 1) * 8;    // W-load k offset

    float acc[8][4] = {};

    for (int kb = 0; kb < K; kb += BK) {
        int arow = block_m + ar;
        float4 av = make_float4(0.f, 0.f, 0.f, 0.f);
        if (arow < M) av = *(const float4*)(A + (size_t)arow * K + kb + ak);
        *(float4*)(&As[ar][ak]) = av;

        const float* wrow = W + (size_t)wn * K + kb + wk0;
        float4 w0 = *(const float4*)(wrow);
        float4 w1 = *(const float4*)(wrow + 4);
        Bs[wk0 + 0][wn] = w0.x; Bs[wk0 + 1][wn] = w0.y;
        Bs[wk0 + 2][wn] = w0.z; Bs[wk0 + 3][wn] = w0.w;
        Bs[wk0 + 4][wn] = w1.x; Bs[wk0 + 5][wn] = w1.y;
        Bs[wk0 + 6][wn] = w1.z; Bs[wk0 + 7][wn] = w1.w;
        __syncthreads();

#pragma unroll
        for (int k = 0; k < BK; ++k) {
            float4 b = *(const float4*)(&Bs[k][tc * 4]);
#pragma unroll
            for (int i = 0; i < 8; ++i) {
                float a = As[tr * 8 + i][k];
                acc[i][0] += a * b.x; acc[i][1] += a * b.y;
                acc[i][2] += a * b.z; acc[i][3] += a * b.w;
            }
        }
        __syncthreads();
    }

#pragma unroll
    for (int i = 0; i < 8; ++i) {
        int row = block_m + tr * 8 + i;
        if (row < M) {
            float4 v = make_float4(acc[i][0], acc[i][1], acc[i][2], acc[i][3]);
            *(float4*)(C + (size_t)row * BN + tc * 4) = v;
        }
    }
}

// ---------------- edge aggregation (atomic scatter) -------------------------
// one wave per edge; 64 lanes x float2 = 128 features
__global__ __launch_bounds__(256) void aggregate(const float* __restrict__ h,
                                                 const int* __restrict__ src,
                                                 const int* __restrict__ dst,
                                                 const float* __restrict__ dinv,
                                                 float* __restrict__ outbuf, int E) {
    int wid = (blockIdx.x * blockDim.x + threadIdx.x) >> 6;
    int lane = threadIdx.x & 63;
    int nw = (gridDim.x * blockDim.x) >> 6;
    for (int e = wid; e < E; e += nw) {
        int s = src[e], d = dst[e];
        float w = dinv[s] * dinv[d];
        float2 v = ((const float2*)(h + (size_t)s * HID))[lane];
        float* op = outbuf + (size_t)d * HID + lane * 2;
        atomicAdd(op,     v.x * w);
        atomicAdd(op + 1, v.y * w);
    }
}

// ---------------- post-process kernels --------------------------------------
// layer1: h = dropout(relu(agg + H1*dinv^2 + b1))   (self-loop folded in)
__global__ __launch_bounds__(256) void post1(float* __restrict__ agg,
                                             const float* __restrict__ H1,
                                             const float* __restrict__ dinv,
                                             const float* __restrict__ b1,
                                             int total) {
    int idx = blockIdx.x * blockDim.x + threadIdx.x;
    if (idx >= total) return;
    int node = idx >> 7;
    int f = idx & 127;
    float di = dinv[node];
    float v = agg[idx] + H1[idx] * di * di + b1[f];
    v = fmaxf(v, 0.0f);
    v *= dropout_scale((unsigned)idx);
    agg[idx] = v;
}

// layer2: out += H2*dinv^2 + b2
__global__ __launch_bounds__(256) void post2(float* __restrict__ out,
                                             const float* __restrict__ H2,
                                             const float* __restrict__ dinv,
                                             const float* __restrict__ b2,
                                             int total) {
    int idx = blockIdx.x * blockDim.x + threadIdx.x;
    if (idx >= total) return;
    int node = idx >> 7;
    int f = idx & 127;
    float di = dinv[node];
    out[idx] += H2[idx] * di * di + b2[f];
}

// ---------------- launcher ---------------------------------------------------
extern "C" void kernel_launch(void* const* d_in, const int* in_sizes, int n_in,
                              void* d_out, int out_size, void* d_ws, size_t ws_size,
                              hipStream_t stream) {
    const float* X  = (const float*)d_in[0];
    const int*   ei = (const int*)d_in[1];
    const float* W1 = (const float*)d_in[2];
    const float* b1 = (const float*)d_in[3];
    const float* W2 = (const float*)d_in[4];
    const float* b2 = (const float*)d_in[5];
    float* out = (float*)d_out;

    const int N = in_sizes[0] / IN_DIM;      // 100000
    const int E = in_sizes[1] / 2;           // 1600000
    const int* src = ei;
    const int* dst = ei + E;
    const int total = N * HID;               // 12.8M

    char* ws = (char*)d_ws;
    float* bufA = (float*)ws;                                  // H1 / H2
    float* bufB = (float*)(ws + (size_t)total * 4);            // agg1 / h1drop
    float* dinv = (float*)(ws + 2 * (size_t)total * 4);        // deg -> dinv

    // zero accumulation buffers (stream-ordered, capture-legal)
    hipMemsetAsync(bufB, 0, (size_t)total * 4, stream);
    hipMemsetAsync(out,  0, (size_t)total * 4, stream);

    // degrees
    deg_init<<<(N + 255) / 256, 256, 0, stream>>>(dinv, N);
    deg_count<<<2048, 256, 0, stream>>>(dst, dinv, E);
    deg_rsqrt<<<(N + 255) / 256, 256, 0, stream>>>(dinv, N);

    // layer 1
    gemm_xwT<<<(N + BM - 1) / BM, 256, 0, stream>>>(X, W1, bufA, N, IN_DIM);
    aggregate<<<8192, 256, 0, stream>>>(bufA, src, dst, dinv, bufB, E);
    post1<<<(total + 255) / 256, 256, 0, stream>>>(bufB, bufA, dinv, b1, total);

    // layer 2
    gemm_xwT<<<(N + BM - 1) / BM, 256, 0, stream>>>(bufB, W2, bufA, N, HID);
    aggregate<<<8192, 256, 0, stream>>>(bufA, src, dst, dinv, out, E);
    post2<<<(total + 255) / 256, 256, 0, stream>>>(out, bufA, dinv, b2, total);
}

// Round 3
// 637.032 us; speedup vs baseline: 4.5806x; 4.5806x over previous
//
#include <hip/hip_runtime.h>
#include <hip/hip_bf16.h>
#include <stdint.h>

#define IN_DIM 256
#define HID 128

// ---------------- threefry2x32 dropout (JAX partitionable path) -------------
// key = jax.random.key(42) -> (0,42); bits = x0^x1 of threefry2x32(hi=0, lo=idx)
__device__ __forceinline__ unsigned rotl32(unsigned x, int r) {
    return (x << r) | (x >> (32 - r));
}

__device__ __forceinline__ float dropout_scale(unsigned idx) {
    const unsigned ks0 = 0u, ks1 = 42u, ks2 = 0x1BD11BF0u;
    unsigned x0 = 0u + ks0;
    unsigned x1 = idx + ks1;
#define TF_ROUND(r) { x0 += x1; x1 = rotl32(x1, r); x1 ^= x0; }
    TF_ROUND(13) TF_ROUND(15) TF_ROUND(26) TF_ROUND(6)
    x0 += ks1; x1 += ks2 + 1u;
    TF_ROUND(17) TF_ROUND(29) TF_ROUND(16) TF_ROUND(24)
    x0 += ks2; x1 += ks0 + 2u;
    TF_ROUND(13) TF_ROUND(15) TF_ROUND(26) TF_ROUND(6)
    x0 += ks0; x1 += ks1 + 3u;
    TF_ROUND(17) TF_ROUND(29) TF_ROUND(16) TF_ROUND(24)
    x0 += ks1; x1 += ks2 + 4u;
    TF_ROUND(13) TF_ROUND(15) TF_ROUND(26) TF_ROUND(6)
    x0 += ks2; x1 += ks0 + 5u;
#undef TF_ROUND
    unsigned bits = x0 ^ x1;
    float u = __uint_as_float(0x3F800000u | (bits >> 9)) - 1.0f;
    return (u < 0.9f) ? (1.0f / 0.9f) : 0.0f;
}

// ---------------- degree / histogram ----------------------------------------
__global__ void hist_dst(const int* __restrict__ dst, int* __restrict__ cnt, int E) {
    int stride = gridDim.x * blockDim.x;
    for (int i = blockIdx.x * blockDim.x + threadIdx.x; i < E; i += stride)
        atomicAdd(&cnt[dst[i]], 1);
}

__global__ void dinv_from_cnt(const int* __restrict__ cnt, float* __restrict__ dinv, int n) {
    int i = blockIdx.x * blockDim.x + threadIdx.x;
    if (i < n) dinv[i] = rsqrtf((float)(cnt[i] + 1)); // +1 self-loop
}

// ---------------- 3-phase exclusive scan (1024 elems / block) ---------------
__global__ __launch_bounds__(256) void scan_local(const int* __restrict__ cnt,
                                                  int* __restrict__ offs,
                                                  int* __restrict__ bsum, int n) {
    __shared__ int lds[256];
    int b = blockIdx.x, t = threadIdx.x;
    int base = b * 1024 + t * 4;
    int x0 = 0, x1 = 0, x2 = 0, x3 = 0;
    if (base + 3 < n) {
        int4 v = *(const int4*)(cnt + base);
        x0 = v.x; x1 = v.y; x2 = v.z; x3 = v.w;
    } else {
        if (base + 0 < n) x0 = cnt[base + 0];
        if (base + 1 < n) x1 = cnt[base + 1];
        if (base + 2 < n) x2 = cnt[base + 2];
        if (base + 3 < n) x3 = cnt[base + 3];
    }
    int s0 = x0, s1 = s0 + x1, s2 = s1 + x2, s3 = s2 + x3;
    lds[t] = s3;
    __syncthreads();
    for (int d = 1; d < 256; d <<= 1) {
        int val = lds[t];
        int add = (t >= d) ? lds[t - d] : 0;
        __syncthreads();
        lds[t] = val + add;
        __syncthreads();
    }
    int excl = lds[t] - s3;
    if (base + 0 < n) offs[base + 0] = excl;
    if (base + 1 < n) offs[base + 1] = excl + s0;
    if (base + 2 < n) offs[base + 2] = excl + s1;
    if (base + 3 < n) offs[base + 3] = excl + s2;
    if (t == 255) bsum[b] = lds[255];
}

__global__ __launch_bounds__(256) void scan_bsums(int* __restrict__ bsum, int nb) {
    __shared__ int lds[256];
    int t = threadIdx.x;
    int orig = (t < nb) ? bsum[t] : 0;
    lds[t] = orig;
    __syncthreads();
    for (int d = 1; d < 256; d <<= 1) {
        int val = lds[t];
        int add = (t >= d) ? lds[t - d] : 0;
        __syncthreads();
        lds[t] = val + add;
        __syncthreads();
    }
    if (t < nb) bsum[t] = lds[t] - orig; // exclusive
}

// offs += scanned block sums; cursor (aliased onto cnt) = offs
__global__ void scan_add_copy(int* __restrict__ offs, const int* __restrict__ bsum,
                              int* __restrict__ cursor, int n) {
    int i = blockIdx.x * blockDim.x + threadIdx.x;
    if (i < n) {
        int v = offs[i] + bsum[i >> 10];
        offs[i] = v;
        cursor[i] = v;
    }
}

__global__ void scatter_edges(const int* __restrict__ src, const int* __restrict__ dst,
                              int* __restrict__ cursor, int* __restrict__ ssrc, int E) {
    int stride = gridDim.x * blockDim.x;
    for (int e = blockIdx.x * blockDim.x + threadIdx.x; e < E; e += stride) {
        int pos = atomicAdd(&cursor[dst[e]], 1);
        ssrc[pos] = src[e];
    }
}

// ---------------- fp32 GEMM: C[M x 128] = A[M x K] @ W[128 x K]^T -----------
#define BM 64
#define BN 128
#define BK 16
__global__ __launch_bounds__(256) void gemm_xwT(const float* __restrict__ A,
                                                const float* __restrict__ W,
                                                float* __restrict__ C,
                                                int M, int K) {
    __shared__ float As[BM][BK];
    __shared__ float Bs[BK][BN];
    const int block_m = blockIdx.x * BM;
    const int t = threadIdx.x;
    const int tr = t >> 5;
    const int tc = t & 31;
    const int ar = t >> 2;
    const int ak = (t & 3) * 4;
    const int wn = t >> 1;
    const int wk0 = (t & 1) * 8;

    float acc[8][4] = {};

    for (int kb = 0; kb < K; kb += BK) {
        int arow = block_m + ar;
        float4 av = make_float4(0.f, 0.f, 0.f, 0.f);
        if (arow < M) av = *(const float4*)(A + (size_t)arow * K + kb + ak);
        *(float4*)(&As[ar][ak]) = av;

        const float* wrow = W + (size_t)wn * K + kb + wk0;
        float4 w0 = *(const float4*)(wrow);
        float4 w1 = *(const float4*)(wrow + 4);
        Bs[wk0 + 0][wn] = w0.x; Bs[wk0 + 1][wn] = w0.y;
        Bs[wk0 + 2][wn] = w0.z; Bs[wk0 + 3][wn] = w0.w;
        Bs[wk0 + 4][wn] = w1.x; Bs[wk0 + 5][wn] = w1.y;
        Bs[wk0 + 6][wn] = w1.z; Bs[wk0 + 7][wn] = w1.w;
        __syncthreads();

#pragma unroll
        for (int k = 0; k < BK; ++k) {
            float4 b = *(const float4*)(&Bs[k][tc * 4]);
#pragma unroll
            for (int i = 0; i < 8; ++i) {
                float a = As[tr * 8 + i][k];
                acc[i][0] += a * b.x; acc[i][1] += a * b.y;
                acc[i][2] += a * b.z; acc[i][3] += a * b.w;
            }
        }
        __syncthreads();
    }

#pragma unroll
    for (int i = 0; i < 8; ++i) {
        int row = block_m + tr * 8 + i;
        if (row < M) {
            float4 v = make_float4(acc[i][0], acc[i][1], acc[i][2], acc[i][3]);
            *(float4*)(C + (size_t)row * BN + tc * 4) = v;
        }
    }
}

// ---------------- CSR gather aggregation, fused epilogue --------------------
// MODE 1: out = dropout(relu(agg + b));  MODE 2: out = agg + b
template <int MODE>
__global__ __launch_bounds__(256) void aggregate_csr(const float* __restrict__ h,
                                                     const int* __restrict__ soff,
                                                     const int* __restrict__ ssrc,
                                                     const float* __restrict__ dinv,
                                                     const float* __restrict__ bias,
                                                     float* __restrict__ outp,
                                                     int N, int E) {
    int n = blockIdx.x * 4 + (threadIdx.x >> 6);
    if (n >= N) return;
    int lane = threadIdx.x & 63;
    int start = soff[n];
    int end = (n + 1 < N) ? soff[n + 1] : E;
    float dn = dinv[n];
    const float2* __restrict__ h2 = (const float2*)h;

    float2 acc = make_float2(0.f, 0.f);
    int s_nxt = (start < end) ? ssrc[start] : 0;
    for (int i = start; i < end; ++i) {
        int s = s_nxt;
        if (i + 1 < end) s_nxt = ssrc[i + 1];
        float w = dinv[s];
        float2 v = h2[(size_t)s * 64 + lane];
        acc.x = fmaf(w, v.x, acc.x);
        acc.y = fmaf(w, v.y, acc.y);
    }
    // self-loop + dest-side norm: dn*(sum + dn*h[n])
    float2 hv = h2[(size_t)n * 64 + lane];
    acc.x = (acc.x + dn * hv.x) * dn;
    acc.y = (acc.y + dn * hv.y) * dn;
    float2 bv = ((const float2*)bias)[lane];
    acc.x += bv.x;
    acc.y += bv.y;
    if (MODE == 1) {
        unsigned idx = (unsigned)n * 128u + (unsigned)lane * 2u;
        acc.x = fmaxf(acc.x, 0.f) * dropout_scale(idx);
        acc.y = fmaxf(acc.y, 0.f) * dropout_scale(idx + 1u);
    }
    ((float2*)outp)[(size_t)n * 64 + lane] = acc;
}

// ---------------- fallback (atomic scatter) path ----------------------------
__global__ void deg_init(float* deg, int n) {
    int i = blockIdx.x * blockDim.x + threadIdx.x;
    if (i < n) deg[i] = 1.0f;
}
__global__ void deg_count(const int* __restrict__ dst, float* __restrict__ deg, int E) {
    int stride = gridDim.x * blockDim.x;
    for (int i = blockIdx.x * blockDim.x + threadIdx.x; i < E; i += stride)
        atomicAdd(&deg[dst[i]], 1.0f);
}
__global__ void deg_rsqrt(float* deg, int n) {
    int i = blockIdx.x * blockDim.x + threadIdx.x;
    if (i < n) deg[i] = 1.0f / sqrtf(deg[i]);
}
__global__ __launch_bounds__(256) void aggregate_atomic(const float* __restrict__ h,
                                                        const int* __restrict__ src,
                                                        const int* __restrict__ dst,
                                                        const float* __restrict__ dinv,
                                                        float* __restrict__ outbuf, int E) {
    int wid = (blockIdx.x * blockDim.x + threadIdx.x) >> 6;
    int lane = threadIdx.x & 63;
    int nw = (gridDim.x * blockDim.x) >> 6;
    for (int e = wid; e < E; e += nw) {
        int s = src[e], d = dst[e];
        float w = dinv[s] * dinv[d];
        float2 v = ((const float2*)(h + (size_t)s * HID))[lane];
        float* op = outbuf + (size_t)d * HID + lane * 2;
        atomicAdd(op, v.x * w);
        atomicAdd(op + 1, v.y * w);
    }
}
__global__ __launch_bounds__(256) void post1(float* __restrict__ agg,
                                             const float* __restrict__ H1,
                                             const float* __restrict__ dinv,
                                             const float* __restrict__ b1, int total) {
    int idx = blockIdx.x * blockDim.x + threadIdx.x;
    if (idx >= total) return;
    int node = idx >> 7;
    int f = idx & 127;
    float di = dinv[node];
    float v = agg[idx] + H1[idx] * di * di + b1[f];
    v = fmaxf(v, 0.0f);
    v *= dropout_scale((unsigned)idx);
    agg[idx] = v;
}
__global__ __launch_bounds__(256) void post2(float* __restrict__ out,
                                             const float* __restrict__ H2,
                                             const float* __restrict__ dinv,
                                             const float* __restrict__ b2, int total) {
    int idx = blockIdx.x * blockDim.x + threadIdx.x;
    if (idx >= total) return;
    int node = idx >> 7;
    int f = idx & 127;
    float di = dinv[node];
    out[idx] += H2[idx] * di * di + b2[f];
}

// ---------------- launcher ---------------------------------------------------
extern "C" void kernel_launch(void* const* d_in, const int* in_sizes, int n_in,
                              void* d_out, int out_size, void* d_ws, size_t ws_size,
                              hipStream_t stream) {
    const float* X  = (const float*)d_in[0];
    const int*   ei = (const int*)d_in[1];
    const float* W1 = (const float*)d_in[2];
    const float* b1 = (const float*)d_in[3];
    const float* W2 = (const float*)d_in[4];
    const float* b2 = (const float*)d_in[5];
    float* out = (float*)d_out;

    const int N = in_sizes[0] / IN_DIM;  // 100000
    const int E = in_sizes[1] / 2;       // 1600000
    const int* src = ei;
    const int* dst = ei + E;
    const int total = N * HID;
    const size_t tot4 = (size_t)total * 4;
    const size_t N4 = (size_t)N * 4;

    char* ws = (char*)d_ws;
    float* bufA = (float*)ws;                         // H1 / H2
    float* bufB = (float*)(ws + tot4);                // h1drop
    float* dinv = (float*)(ws + 2 * tot4);
    int* cnt    = (int*)(ws + 2 * tot4 + N4);         // histogram, later cursor
    int* offs   = (int*)(ws + 2 * tot4 + 2 * N4);
    int* bsum   = (int*)(ws + 2 * tot4 + 3 * N4);
    int* ssrc   = (int*)(ws + 2 * tot4 + 3 * N4 + 4096);
    const size_t need = 2 * tot4 + 3 * N4 + 4096 + (size_t)E * 4;

    const int nb = (N + 1023) / 1024;  // scan blocks (<=256 supported)

    if (ws_size >= need && nb <= 256) {
        // ---------- CSR gather path ----------
        hipMemsetAsync(cnt, 0, N4, stream);
        hist_dst<<<2048, 256, 0, stream>>>(dst, cnt, E);
        dinv_from_cnt<<<(N + 255) / 256, 256, 0, stream>>>(cnt, dinv, N);
        scan_local<<<nb, 256, 0, stream>>>(cnt, offs, bsum, N);
        scan_bsums<<<1, 256, 0, stream>>>(bsum, nb);
        scan_add_copy<<<(N + 255) / 256, 256, 0, stream>>>(offs, bsum, cnt, N);
        scatter_edges<<<2048, 256, 0, stream>>>(src, dst, cnt, ssrc, E);

        gemm_xwT<<<(N + BM - 1) / BM, 256, 0, stream>>>(X, W1, bufA, N, IN_DIM);
        aggregate_csr<1><<<(N + 3) / 4, 256, 0, stream>>>(bufA, offs, ssrc, dinv, b1,
                                                          bufB, N, E);
        gemm_xwT<<<(N + BM - 1) / BM, 256, 0, stream>>>(bufB, W2, bufA, N, HID);
        aggregate_csr<2><<<(N + 3) / 4, 256, 0, stream>>>(bufA, offs, ssrc, dinv, b2,
                                                          out, N, E);
    } else {
        // ---------- fallback: atomic scatter path ----------
        hipMemsetAsync(bufB, 0, tot4, stream);
        hipMemsetAsync(out, 0, tot4, stream);
        deg_init<<<(N + 255) / 256, 256, 0, stream>>>(dinv, N);
        deg_count<<<2048, 256, 0, stream>>>(dst, dinv, E);
        deg_rsqrt<<<(N + 255) / 256, 256, 0, stream>>>(dinv, N);
        gemm_xwT<<<(N + BM - 1) / BM, 256, 0, stream>>>(X, W1, bufA, N, IN_DIM);
        aggregate_atomic<<<8192, 256, 0, stream>>>(bufA, src, dst, dinv, bufB, E);
        post1<<<(total + 255) / 256, 256, 0, stream>>>(bufB, bufA, dinv, b1, total);
        gemm_xwT<<<(N + BM - 1) / BM, 256, 0, stream>>>(bufB, W2, bufA, N, HID);
        aggregate_atomic<<<8192, 256, 0, stream>>>(bufA, src, dst, dinv, out, E);
        post2<<<(total + 255) / 256, 256, 0, stream>>>(out, bufA, dinv, b2, total);
    }
}

// Round 4
// 504.964 us; speedup vs baseline: 5.7787x; 1.2615x over previous
//
#include <hip/hip_runtime.h>
#include <stdint.h>

#define IN_DIM 256
#define HID 128

typedef __attribute__((ext_vector_type(8))) short short8v;   // 8 bf16 (4 VGPRs)
typedef __attribute__((ext_vector_type(4))) float f32x4;     // MFMA acc

// ---------------- bf16 helpers ----------------------------------------------
__device__ __forceinline__ unsigned short f2bf(float f) {
    unsigned u = __float_as_uint(f);
    unsigned rnd = 0x7FFFu + ((u >> 16) & 1u);
    return (unsigned short)((u + rnd) >> 16);
}
__device__ __forceinline__ float bflo(unsigned v) { return __uint_as_float(v << 16); }
__device__ __forceinline__ float bfhi(unsigned v) { return __uint_as_float(v & 0xFFFF0000u); }

// ---------------- threefry2x32 dropout (JAX partitionable path) -------------
__device__ __forceinline__ unsigned rotl32(unsigned x, int r) {
    return (x << r) | (x >> (32 - r));
}
__device__ __forceinline__ float dropout_scale(unsigned idx) {
    const unsigned ks0 = 0u, ks1 = 42u, ks2 = 0x1BD11BF0u;
    unsigned x0 = 0u + ks0;
    unsigned x1 = idx + ks1;
#define TF_ROUND(r) { x0 += x1; x1 = rotl32(x1, r); x1 ^= x0; }
    TF_ROUND(13) TF_ROUND(15) TF_ROUND(26) TF_ROUND(6)
    x0 += ks1; x1 += ks2 + 1u;
    TF_ROUND(17) TF_ROUND(29) TF_ROUND(16) TF_ROUND(24)
    x0 += ks2; x1 += ks0 + 2u;
    TF_ROUND(13) TF_ROUND(15) TF_ROUND(26) TF_ROUND(6)
    x0 += ks0; x1 += ks1 + 3u;
    TF_ROUND(17) TF_ROUND(29) TF_ROUND(16) TF_ROUND(24)
    x0 += ks1; x1 += ks2 + 4u;
    TF_ROUND(13) TF_ROUND(15) TF_ROUND(26) TF_ROUND(6)
    x0 += ks2; x1 += ks0 + 5u;
#undef TF_ROUND
    unsigned bits = x0 ^ x1;
    float u = __uint_as_float(0x3F800000u | (bits >> 9)) - 1.0f;
    return (u < 0.9f) ? (1.0f / 0.9f) : 0.0f;
}

// ---------------- histogram / degree ----------------------------------------
__global__ void hist_dst(const int* __restrict__ dst, int* __restrict__ cnt, int E) {
    int stride = gridDim.x * blockDim.x;
    for (int i = blockIdx.x * blockDim.x + threadIdx.x; i < E; i += stride)
        atomicAdd(&cnt[dst[i]], 1);
}
__global__ void dinv_from_cnt(const int* __restrict__ cnt, float* __restrict__ dinv, int n) {
    int i = blockIdx.x * blockDim.x + threadIdx.x;
    if (i < n) dinv[i] = rsqrtf((float)(cnt[i] + 1));
}

// ---------------- 3-phase exclusive scan ------------------------------------
__global__ __launch_bounds__(256) void scan_local(const int* __restrict__ cnt,
                                                  int* __restrict__ offs,
                                                  int* __restrict__ bsum, int n) {
    __shared__ int lds[256];
    int b = blockIdx.x, t = threadIdx.x;
    int base = b * 1024 + t * 4;
    int x0 = 0, x1 = 0, x2 = 0, x3 = 0;
    if (base + 3 < n) {
        int4 v = *(const int4*)(cnt + base);
        x0 = v.x; x1 = v.y; x2 = v.z; x3 = v.w;
    } else {
        if (base + 0 < n) x0 = cnt[base + 0];
        if (base + 1 < n) x1 = cnt[base + 1];
        if (base + 2 < n) x2 = cnt[base + 2];
        if (base + 3 < n) x3 = cnt[base + 3];
    }
    int s0 = x0, s1 = s0 + x1, s2 = s1 + x2, s3 = s2 + x3;
    lds[t] = s3;
    __syncthreads();
    for (int d = 1; d < 256; d <<= 1) {
        int val = lds[t];
        int add = (t >= d) ? lds[t - d] : 0;
        __syncthreads();
        lds[t] = val + add;
        __syncthreads();
    }
    int excl = lds[t] - s3;
    if (base + 0 < n) offs[base + 0] = excl;
    if (base + 1 < n) offs[base + 1] = excl + s0;
    if (base + 2 < n) offs[base + 2] = excl + s1;
    if (base + 3 < n) offs[base + 3] = excl + s2;
    if (t == 255) bsum[b] = lds[255];
}
__global__ __launch_bounds__(256) void scan_bsums(int* __restrict__ bsum, int nb) {
    __shared__ int lds[256];
    int t = threadIdx.x;
    int orig = (t < nb) ? bsum[t] : 0;
    lds[t] = orig;
    __syncthreads();
    for (int d = 1; d < 256; d <<= 1) {
        int val = lds[t];
        int add = (t >= d) ? lds[t - d] : 0;
        __syncthreads();
        lds[t] = val + add;
        __syncthreads();
    }
    if (t < nb) bsum[t] = lds[t] - orig;
}
__global__ void scan_add_copy(int* __restrict__ offs, const int* __restrict__ bsum,
                              int* __restrict__ cursor, int n) {
    int i = blockIdx.x * blockDim.x + threadIdx.x;
    if (i < n) {
        int v = offs[i] + bsum[i >> 10];
        offs[i] = v;
        cursor[i] = v;
    }
}
__global__ void scatter_edges(const int* __restrict__ src, const int* __restrict__ dst,
                              int* __restrict__ cursor, int* __restrict__ ssrc, int E) {
    int stride = gridDim.x * blockDim.x;
    for (int e = blockIdx.x * blockDim.x + threadIdx.x; e < E; e += stride) {
        int pos = atomicAdd(&cursor[dst[e]], 1);
        ssrc[pos] = src[e];
    }
}

// ---------------- weight fp32 -> bf16 ---------------------------------------
__global__ void cvt_w(const float* __restrict__ W, unsigned short* __restrict__ Wb, int n) {
    int i = blockIdx.x * blockDim.x + threadIdx.x;
    if (i < n) Wb[i] = f2bf(W[i]);
}

// ---------------- bf16 MFMA GEMM: C[M x 128] = A[M x K] @ W[128 x K]^T ------
// 256 thr (4 waves); block tile 64 rows; W fully LDS-resident (bf16).
// A_BF16=0: A fp32 (converted while staging); A_BF16=1: A bf16.
#define WP 264   // padded W row stride (ushorts) -> 2-way banks (free)
#define AP 40    // padded A row stride (ushorts)
template <int A_BF16>
__global__ __launch_bounds__(256) void gemm_mfma(const void* __restrict__ Ap,
                                                 const unsigned short* __restrict__ Wb,
                                                 unsigned short* __restrict__ C,
                                                 int M, int K) {
    __shared__ unsigned short Wlds[128 * WP];
    __shared__ unsigned short Alds[64 * AP];
    const int t = threadIdx.x;
    const int bm = blockIdx.x * 64;

    // stage W (entirely): chunks of 8 bf16
    const int kc = K >> 3;               // 16B chunks per row
    for (int c = t; c < 128 * kc; c += 256) {
        int row = c / kc, ko = c % kc;
        short8v w = *(const short8v*)(Wb + (size_t)row * K + ko * 8);
        *(short8v*)(&Wlds[row * WP + ko * 8]) = w;
    }

    const int w = t >> 6, l = t & 63;
    const int lr = l & 15, lk = l >> 4;
    const int sr = t >> 2, sc = t & 3;          // staging: row, k-chunk

    f32x4 acc[8] = {};

    for (int kb = 0; kb < K; kb += 32) {
        // stage A tile [64][32]
        if (A_BF16) {
            short8v v = {};
            if (bm + sr < M)
                v = *(const short8v*)((const unsigned short*)Ap + (size_t)(bm + sr) * K + kb + sc * 8);
            *(short8v*)(&Alds[sr * AP + sc * 8]) = v;
        } else {
            short8v u = {};
            if (bm + sr < M) {
                const float* arow = (const float*)Ap + (size_t)(bm + sr) * K + kb + sc * 8;
                float4 f0 = *(const float4*)(arow);
                float4 f1 = *(const float4*)(arow + 4);
                u[0] = (short)f2bf(f0.x); u[1] = (short)f2bf(f0.y);
                u[2] = (short)f2bf(f0.z); u[3] = (short)f2bf(f0.w);
                u[4] = (short)f2bf(f1.x); u[5] = (short)f2bf(f1.y);
                u[6] = (short)f2bf(f1.z); u[7] = (short)f2bf(f1.w);
            }
            *(short8v*)(&Alds[sr * AP + sc * 8]) = u;
        }
        __syncthreads();

        short8v a = *(const short8v*)(&Alds[(w * 16 + lr) * AP + lk * 8]);
#pragma unroll
        for (int cb = 0; cb < 8; ++cb) {
            short8v b = *(const short8v*)(&Wlds[(cb * 16 + lr) * WP + kb + lk * 8]);
            acc[cb] = __builtin_amdgcn_mfma_f32_16x16x32_bf16(a, b, acc[cb], 0, 0, 0);
        }
        __syncthreads();
    }

    // epilogue: C/D layout col=lane&15, row=(lane>>4)*4+reg
#pragma unroll
    for (int cb = 0; cb < 8; ++cb) {
#pragma unroll
        for (int j = 0; j < 4; ++j) {
            int row = bm + w * 16 + lk * 4 + j;
            int col = cb * 16 + lr;
            if (row < M) C[(size_t)row * 128 + col] = f2bf(acc[cb][j]);
        }
    }
}

// ---------------- CSR gather aggregation (bf16 h), fused epilogue -----------
// MODE 1: out(bf16) = dropout(relu(agg + b));  MODE 2: out(fp32) = agg + b
template <int MODE>
__global__ __launch_bounds__(256) void aggregate_csr(const unsigned* __restrict__ h,
                                                     const int* __restrict__ soff,
                                                     const int* __restrict__ ssrc,
                                                     const float* __restrict__ dinv,
                                                     const float* __restrict__ bias,
                                                     void* __restrict__ outp,
                                                     int N, int E) {
    int n = blockIdx.x * 4 + (threadIdx.x >> 6);
    if (n >= N) return;
    int lane = threadIdx.x & 63;
    int start = soff[n];
    int end = (n + 1 < N) ? soff[n + 1] : E;
    float dn = dinv[n];

    float ax = 0.f, ay = 0.f;
    int s_nxt = (start < end) ? ssrc[start] : 0;
    for (int i = start; i < end; ++i) {
        int s = s_nxt;
        if (i + 1 < end) s_nxt = ssrc[i + 1];
        float wgt = dinv[s];
        unsigned v = h[(size_t)s * 64 + lane];
        ax = fmaf(wgt, bflo(v), ax);
        ay = fmaf(wgt, bfhi(v), ay);
    }
    unsigned hv = h[(size_t)n * 64 + lane];
    ax = (ax + dn * bflo(hv)) * dn;
    ay = (ay + dn * bfhi(hv)) * dn;
    float2 bv = ((const float2*)bias)[lane];
    ax += bv.x;
    ay += bv.y;
    if (MODE == 1) {
        unsigned idx = (unsigned)n * 128u + (unsigned)lane * 2u;
        ax = fmaxf(ax, 0.f) * dropout_scale(idx);
        ay = fmaxf(ay, 0.f) * dropout_scale(idx + 1u);
        ((unsigned*)outp)[(size_t)n * 64 + lane] =
            (unsigned)f2bf(ax) | ((unsigned)f2bf(ay) << 16);
    } else {
        ((float2*)outp)[(size_t)n * 64 + lane] = make_float2(ax, ay);
    }
}

// ---------------- launcher ---------------------------------------------------
extern "C" void kernel_launch(void* const* d_in, const int* in_sizes, int n_in,
                              void* d_out, int out_size, void* d_ws, size_t ws_size,
                              hipStream_t stream) {
    const float* X  = (const float*)d_in[0];
    const int*   ei = (const int*)d_in[1];
    const float* W1 = (const float*)d_in[2];
    const float* b1 = (const float*)d_in[3];
    const float* W2 = (const float*)d_in[4];
    const float* b2 = (const float*)d_in[5];
    float* out = (float*)d_out;

    const int N = in_sizes[0] / IN_DIM;  // 100000
    const int E = in_sizes[1] / 2;       // 1600000
    const int* src = ei;
    const int* dst = ei + E;
    const int total = N * HID;           // 12.8M
    const size_t N4 = (size_t)N * 4;
    const size_t tot2 = (size_t)total * 2;   // bf16 h buffer bytes

    char* ws = (char*)d_ws;
    unsigned short* hA = (unsigned short*)ws;            // h1 pre-act / h2 pre-act
    unsigned short* hB = (unsigned short*)(ws + tot2);   // h1 post-dropout (bf16)
    float* dinv = (float*)(ws + 2 * tot2);
    int* cnt    = (int*)(ws + 2 * tot2 + N4);
    int* offs   = (int*)(ws + 2 * tot2 + 2 * N4);
    int* bsum   = (int*)(ws + 2 * tot2 + 3 * N4);
    int* ssrc   = (int*)(ws + 2 * tot2 + 3 * N4 + 4096);
    unsigned short* Wb1 = (unsigned short*)(ws + 2 * tot2 + 3 * N4 + 4096 + (size_t)E * 4);
    unsigned short* Wb2 = Wb1 + HID * IN_DIM;

    const int nb = (N + 1023) / 1024;

    // CSR build + degrees + weight conversion
    hipMemsetAsync(cnt, 0, N4, stream);
    cvt_w<<<(HID * IN_DIM + 255) / 256, 256, 0, stream>>>(W1, Wb1, HID * IN_DIM);
    cvt_w<<<(HID * HID + 255) / 256, 256, 0, stream>>>(W2, Wb2, HID * HID);
    hist_dst<<<2048, 256, 0, stream>>>(dst, cnt, E);
    dinv_from_cnt<<<(N + 255) / 256, 256, 0, stream>>>(cnt, dinv, N);
    scan_local<<<nb, 256, 0, stream>>>(cnt, offs, bsum, N);
    scan_bsums<<<1, 256, 0, stream>>>(bsum, nb);
    scan_add_copy<<<(N + 255) / 256, 256, 0, stream>>>(offs, bsum, cnt, N);
    scatter_edges<<<2048, 256, 0, stream>>>(src, dst, cnt, ssrc, E);

    // layer 1
    gemm_mfma<0><<<(N + 63) / 64, 256, 0, stream>>>(X, Wb1, hA, N, IN_DIM);
    aggregate_csr<1><<<(N + 3) / 4, 256, 0, stream>>>((const unsigned*)hA, offs, ssrc,
                                                      dinv, b1, hB, N, E);
    // layer 2
    gemm_mfma<1><<<(N + 63) / 64, 256, 0, stream>>>(hB, Wb2, hA, N, HID);
    aggregate_csr<2><<<(N + 3) / 4, 256, 0, stream>>>((const unsigned*)hA, offs, ssrc,
                                                      dinv, b2, out, N, E);
}